// Round 12
// baseline (669.028 us; speedup 1.0000x reference)
//
#include <hip/hip_runtime.h>
#include <hip/hip_bf16.h>
#include <stdint.h>

#define T_TOK 4096
#define DDIM  2048
#define HDIM  2048
#define NEXP  8
#define NPAIR (T_TOK * 4)
#define NT    (DDIM / 64)   // 32 K-tiles of 64
#define NITER (NT / 2)      // 16 iterations, 2 K-tiles each

typedef __attribute__((ext_vector_type(8))) short bf16x8;
typedef __attribute__((ext_vector_type(4))) float f32x4;
typedef __attribute__((ext_vector_type(4))) unsigned short u16x4v;
typedef __attribute__((ext_vector_type(8))) unsigned short u16x8v;

__device__ inline unsigned short f2bf(float f) {
  unsigned u = __builtin_bit_cast(unsigned, f);
  unsigned r = (u + 0x7fffu + ((u >> 16) & 1u)) >> 16;
  return (unsigned short)r;
}

// tanh-form GELU via sigmoid; max |dev| vs exact erf-GELU ~3e-4 << threshold headroom.
__device__ inline float gelu_fast(float v) {
  float u = v + 0.044715f * v * v * v;
  return v / (1.0f + __expf(-1.59576912f * u));
}

// ------- transpose + convert: [z][R=2048][C=2048] fp32 -> [z][C][R] bf16 -------
__global__ __launch_bounds__(256) void transpose_conv_kernel(const float* __restrict__ W1,
                                                             const float* __restrict__ W2,
                                                             unsigned short* __restrict__ W1t,
                                                             unsigned short* __restrict__ W2t) {
  __shared__ float t2[64][129];  // [c][r+pad]
  int z = blockIdx.z;
  const float* src = (z < 8 ? W1 : W2) + (size_t)(z & 7) * DDIM * HDIM;
  unsigned short* dst = (z < 8 ? W1t : W2t) + (size_t)(z & 7) * DDIM * HDIM;
  int r0 = blockIdx.x * 128, c0 = blockIdx.y * 64;
  int tid = threadIdx.x;
  int lr = tid >> 4, lc = (tid & 15) * 4;
#pragma unroll
  for (int i = 0; i < 8; ++i) {
    float4 v = *(const float4*)(src + (size_t)(r0 + i * 16 + lr) * 2048 + c0 + lc);
    t2[lc + 0][i * 16 + lr] = v.x;
    t2[lc + 1][i * 16 + lr] = v.y;
    t2[lc + 2][i * 16 + lr] = v.z;
    t2[lc + 3][i * 16 + lr] = v.w;
  }
  __syncthreads();
  int sc = tid >> 4, rc = (tid & 15) * 8;
#pragma unroll
  for (int q = 0; q < 4; ++q) {
    int c = q * 16 + sc;
    u16x8v o;
#pragma unroll
    for (int k = 0; k < 8; ++k) o[k] = f2bf(t2[c][rc + k]);
    *(u16x8v*)(dst + (size_t)(c0 + c) * 2048 + r0 + rc) = o;
  }
}

// ---------------- routing (fused x->bf16 conversion; NO global atomics) ----------------
__global__ __launch_bounds__(256) void routing_kernel(const float* __restrict__ x,
                                                      const float* __restrict__ Wg,
                                                      const float* __restrict__ bg,
                                                      float* __restrict__ logits,
                                                      float* __restrict__ rw,
                                                      int* __restrict__ sel,
                                                      unsigned short* __restrict__ xb) {
  int t = blockIdx.x * 4 + (threadIdx.x >> 6);
  int l = threadIdx.x & 63;
  const float* xr = x + (size_t)t * DDIM;
  float acc[8] = {0.f, 0.f, 0.f, 0.f, 0.f, 0.f, 0.f, 0.f};
#pragma unroll 1
  for (int i = 0; i < 8; ++i) {
    int d = i * 256 + l * 4;
    float4 xv = *(const float4*)(xr + d);
    u16x4v o;
    o[0] = f2bf(xv.x); o[1] = f2bf(xv.y); o[2] = f2bf(xv.z); o[3] = f2bf(xv.w);
    *(u16x4v*)(xb + (size_t)t * DDIM + d) = o;
    const float* wr = Wg + (size_t)d * 8;
    float xq[4] = {xv.x, xv.y, xv.z, xv.w};
#pragma unroll
    for (int q = 0; q < 4; ++q) {
      float4 w0 = *(const float4*)(wr + q * 8);
      float4 w1 = *(const float4*)(wr + q * 8 + 4);
      acc[0] = fmaf(xq[q], w0.x, acc[0]); acc[1] = fmaf(xq[q], w0.y, acc[1]);
      acc[2] = fmaf(xq[q], w0.z, acc[2]); acc[3] = fmaf(xq[q], w0.w, acc[3]);
      acc[4] = fmaf(xq[q], w1.x, acc[4]); acc[5] = fmaf(xq[q], w1.y, acc[5]);
      acc[6] = fmaf(xq[q], w1.z, acc[6]); acc[7] = fmaf(xq[q], w1.w, acc[7]);
    }
  }
#pragma unroll
  for (int e = 0; e < 8; ++e)
#pragma unroll
    for (int off = 32; off > 0; off >>= 1) acc[e] += __shfl_down(acc[e], off);
  if (l == 0) {
    float lg[8];
#pragma unroll
    for (int e = 0; e < 8; ++e) {
      lg[e] = acc[e] + bg[e];
      logits[(size_t)t * 8 + e] = lg[e];
    }
    float mx = lg[0];
#pragma unroll
    for (int e = 1; e < 8; ++e) mx = fmaxf(mx, lg[e]);
    float p[8];
#pragma unroll
    for (int e = 0; e < 8; ++e) p[e] = expf(lg[e] - mx);
    bool used[8] = {false, false, false, false, false, false, false, false};
    float wsum = 0.f; int se[4]; float pv[4];
    for (int k = 0; k < 4; ++k) {
      int best = 0; float bv = -1.f;
      for (int e = 0; e < 8; ++e)
        if (!used[e] && p[e] > bv) { bv = p[e]; best = e; }
      used[best] = true; se[k] = best; pv[k] = bv; wsum += bv;
    }
    for (int k = 0; k < 4; ++k) {
      rw[t * 4 + k] = pv[k] / wsum;
      sel[t * 4 + k] = se[k];
    }
  }
}

// ---------------- expert-slot planning: per-block LDS histograms, 0 hot global atomics ----------------
__global__ __launch_bounds__(256) void hist_kernel(const int* __restrict__ sel,
                                                   int* __restrict__ blkcnt) {
  __shared__ int h[NEXP];
  if (threadIdx.x < NEXP) h[threadIdx.x] = 0;
  __syncthreads();
  int t = blockIdx.x * 256 + threadIdx.x;
#pragma unroll
  for (int k = 0; k < 4; ++k) atomicAdd(&h[sel[t * 4 + k]], 1);
  __syncthreads();
  if (threadIdx.x < NEXP) blkcnt[blockIdx.x * NEXP + threadIdx.x] = h[threadIdx.x];
}

__global__ void plan_kernel(const int* __restrict__ blkcnt, int* __restrict__ cnt,
                            int* __restrict__ off, int* __restrict__ base) {
  if (threadIdx.x == 0) {
    int c[NEXP];
    for (int e = 0; e < NEXP; ++e) c[e] = 0;
    for (int b = 0; b < 16; ++b)
      for (int e = 0; e < NEXP; ++e) { base[b * NEXP + e] = c[e]; c[e] += blkcnt[b * NEXP + e]; }
    int s = 0;
    for (int e = 0; e < NEXP; ++e) { cnt[e] = c[e]; off[e] = s; s += c[e]; }
  }
}

__global__ __launch_bounds__(256) void fill_kernel(const int* __restrict__ sel,
                                                   const float* __restrict__ rw,
                                                   const int* __restrict__ off,
                                                   const int* __restrict__ base,
                                                   int* __restrict__ tok,
                                                   float* __restrict__ wof) {
  __shared__ int h[NEXP];
  if (threadIdx.x < NEXP) h[threadIdx.x] = 0;
  __syncthreads();
  int t = blockIdx.x * 256 + threadIdx.x;
#pragma unroll
  for (int k = 0; k < 4; ++k) {
    int e = sel[t * 4 + k];
    int r = atomicAdd(&h[e], 1);   // LDS atomic: block-local, fast
    int p = off[e] + base[blockIdx.x * NEXP + e] + r;
    tok[p] = t;
    wof[p] = rw[t * 4 + k];
  }
}

#define GLL(g, l) __builtin_amdgcn_global_load_lds(                         \
    (const __attribute__((address_space(1))) void*)(g),                    \
    (__attribute__((address_space(3))) void*)(l), 16, 0, 0)

#define BARX { __builtin_amdgcn_s_barrier(); __builtin_amdgcn_sched_barrier(0); }
#define WAIT4 { asm volatile("s_waitcnt vmcnt(4)" ::: "memory"); __builtin_amdgcn_sched_barrier(0); }
#define WAIT0 { asm volatile("s_waitcnt vmcnt(0)" ::: "memory"); __builtin_amdgcn_sched_barrier(0); }
#define LGKM0 { asm volatile("s_waitcnt lgkmcnt(0)" ::: "memory"); __builtin_amdgcn_sched_barrier(0); }

// =============== MoE GEMM: 256x256 tile, 8 waves, 8-phase, 1 barrier/phase ===============
// R12: ONE compiled kernel for both GEMMs (runtime uniform `mode` flag) — avoids rule-#19
// dual-instantiation codegen perturbation. MODE0 epilogue bounces acc through LDS to emit
// ushort8 (16B/lane) stores = full 64B lines (fixes the measured 2x write amplification).
#define ST_A0(b, ko) { GLL(aP[0] + (ko), ldsc + (b)*65536 +     0 + stDst); GLL(aP[1] + (ko), ldsc + (b)*65536 +  8192 + stDst); }
#define ST_A1(b, ko) { GLL(aP[2] + (ko), ldsc + (b)*65536 + 16384 + stDst); GLL(aP[3] + (ko), ldsc + (b)*65536 + 24576 + stDst); }
#define ST_B0(b, ko) { GLL(bP[0] + (ko), ldsc + (b)*65536 + 32768 + stDst); GLL(bP[1] + (ko), ldsc + (b)*65536 + 40960 + stDst); }
#define ST_B1(b, ko) { GLL(bP[2] + (ko), ldsc + (b)*65536 + 49152 + stDst); GLL(bP[3] + (ko), ldsc + (b)*65536 + 57344 + stDst); }

#define RD_A(Ab, mq) { _Pragma("unroll") for (int i_ = 0; i_ < 4; ++i_) { \
    af[i_][0] = *(const bf16x8*)&(Ab)[((size_t)(wrlr + ((mq)*4 + i_)*16))*64 + c0]; \
    af[i_][1] = *(const bf16x8*)&(Ab)[((size_t)(wrlr + ((mq)*4 + i_)*16))*64 + c1]; } }
#define RD_B(Bb, nq) { _Pragma("unroll") for (int j_ = 0; j_ < 2; ++j_) { \
    bfr[(nq)*2 + j_][0] = *(const bf16x8*)&(Bb)[((size_t)(wclr + ((nq)*2 + j_)*16))*64 + c0]; \
    bfr[(nq)*2 + j_][1] = *(const bf16x8*)&(Bb)[((size_t)(wclr + ((nq)*2 + j_)*16))*64 + c1]; } }
#define MMA_Q(mq, nq) { __builtin_amdgcn_s_setprio(1); \
  _Pragma("unroll") for (int kk_ = 0; kk_ < 2; ++kk_) \
  _Pragma("unroll") for (int i_ = 0; i_ < 4; ++i_) \
  _Pragma("unroll") for (int j_ = 0; j_ < 2; ++j_) \
    acc[(mq)*4 + i_][(nq)*2 + j_] = __builtin_amdgcn_mfma_f32_16x16x32_bf16( \
        af[i_][kk_], bfr[(nq)*2 + j_][kk_], acc[(mq)*4 + i_][(nq)*2 + j_], 0, 0, 0); \
  __builtin_amdgcn_s_setprio(0); }

__global__ __launch_bounds__(512, 2) void moe_gemm_kernel(
    const int mode,
    const unsigned short* __restrict__ A, const unsigned short* __restrict__ Bt,
    const float* __restrict__ bias, const int* __restrict__ cnt,
    const int* __restrict__ off, const int* __restrict__ tok,
    const float* __restrict__ wof, unsigned short* __restrict__ hout,
    float* __restrict__ out) {
  __shared__ unsigned short lds[65536];  // 128 KiB
  const int bid = blockIdx.x;
  const int e   = bid & 7;
  const int rem = bid >> 3;
  const int bm  = rem & 15;
  const int bn  = rem >> 4;
  const int ne  = cnt[e];
  const int m0  = bm * 256;
  if (m0 >= ne) return;
  const int oe  = off[e];
  const int n0  = bn * 256;
  const int tid = threadIdx.x;
  const int w   = tid >> 6;
  const int l   = tid & 63;

  const int srow = tid >> 3;
  const int scg  = ((tid & 7) ^ (srow & 7)) * 8;
  const unsigned short* aP[4];
  const unsigned short* bP[4];
#pragma unroll
  for (int j = 0; j < 4; ++j) {
    int r = m0 + j * 64 + srow;
    if (r > ne - 1) r = ne - 1;
    if (mode == 0)
      aP[j] = A + (size_t)tok[oe + r] * 2048 + scg;
    else
      aP[j] = A + (size_t)(oe + r) * 2048 + scg;
    bP[j] = Bt + ((size_t)e * 2048 + n0 + j * 64 + srow) * 2048 + scg;
  }
  char* ldsc = (char*)lds;
  const int stDst = tid * 16;

  const int wr = (w >> 2) * 128;
  const int wc = (w & 3) * 64;
  const int lr = l & 15;
  const int lq = l >> 4;
  const int cx = lr & 7;
  const int wrlr = wr + lr;
  const int wclr = wc + lr;
  const int c0 = ((0 * 4 + lq) ^ cx) * 8;
  const int c1 = ((1 * 4 + lq) ^ cx) * 8;

  const unsigned short* Ab0 = lds;
  const unsigned short* Bb0 = lds + 16384;
  const unsigned short* Ab1 = lds + 32768;
  const unsigned short* Bb1 = lds + 49152;

  f32x4 acc[8][4];
#pragma unroll
  for (int m = 0; m < 8; ++m)
#pragma unroll
    for (int n = 0; n < 4; ++n) acc[m][n] = (f32x4){0.f, 0.f, 0.f, 0.f};

  ST_B0(0, 0); ST_B1(0, 0); ST_A0(0, 0); ST_A1(0, 0);
  ST_B0(1, 64); ST_B1(1, 64);
  WAIT4; BARX;

#pragma unroll 1
  for (int it = 0; it < NITER; ++it) {
    const int ko1 = (2 * it + 1) * 64;
    const int ko2 = (2 * it + 2) * 64;
    const int ko3 = (2 * it + 3) * 64;
    const bool pf = (it < NITER - 1);
    bf16x8 af[4][2], bfr[4][2];

    ST_A0(1, ko1);
    RD_A(Ab0, 0); RD_B(Bb0, 0);
    MMA_Q(0, 0); BARX;
    ST_A1(1, ko1);
    RD_B(Bb0, 1);
    MMA_Q(0, 1); BARX;
    if (pf) ST_B0(0, ko2);
    RD_A(Ab0, 1);
    MMA_Q(1, 0); BARX;
    if (pf) ST_B1(0, ko2);
    MMA_Q(1, 1);
    if (pf) { WAIT4; } else { WAIT0; }
    BARX;
    if (pf) ST_A0(0, ko2);
    RD_A(Ab1, 0); RD_B(Bb1, 0);
    MMA_Q(0, 0); BARX;
    if (pf) ST_A1(0, ko2);
    RD_B(Bb1, 1);
    MMA_Q(0, 1); BARX;
    if (pf) ST_B0(1, ko3);
    RD_A(Ab1, 1);
    MMA_Q(1, 0); BARX;
    if (pf) ST_B1(1, ko3);
    MMA_Q(1, 1);
    if (pf) { WAIT4; }
    BARX;
  }

  const int rj = lq * 4;
  float bvn[4];
#pragma unroll
  for (int n = 0; n < 4; ++n) bvn[n] = bias[e * 2048 + n0 + wc + n * 16 + lr];

  if (mode == 0) {
    // LDS-bounce epilogue: wave-internal repack -> ushort8 stores (full 64B lines).
    // After the K-loop's final BARX all LDS traffic is done; each wave uses its own
    // 4KB region, so no inter-wave barrier is needed (cross-LANE only -> lgkmcnt fence).
    float* ldsF = (float*)lds;
    const int rr = l >> 2;             // 0..15: row within the wave's 16-row stripe
    const int cc = (l & 3) * 16;       // 0/16/32/48: col group
#pragma unroll 1
    for (int m = 0; m < 8; ++m) {
#pragma unroll
      for (int n = 0; n < 4; ++n)
#pragma unroll
        for (int j = 0; j < 4; ++j)
          ldsF[w * 1024 + (lq * 4 + j) * 64 + n * 16 + lr] = acc[m][n][j] + bvn[n];
      LGKM0;   // rule #18: cross-lane LDS readback needs explicit wait + sched fence
      const int row = m0 + wr + m * 16 + rr;
      if (row < ne) {
        const float* src = &ldsF[w * 1024 + rr * 64 + cc];
        u16x8v o0, o1;
#pragma unroll
        for (int k = 0; k < 8; ++k) o0[k] = f2bf(gelu_fast(src[k]));
#pragma unroll
        for (int k = 0; k < 8; ++k) o1[k] = f2bf(gelu_fast(src[8 + k]));
        unsigned short* dp = hout + (size_t)(oe + row) * 2048 + n0 + wc + cc;
        *(u16x8v*)dp = o0;
        *(u16x8v*)(dp + 8) = o1;
      }
      LGKM0;   // all lanes done reading region before next m overwrites it
    }
  } else {
#pragma unroll
    for (int m = 0; m < 8; ++m) {
      const int rbase = m0 + wr + m * 16 + rj;
#pragma unroll
      for (int j = 0; j < 4; ++j) {
        const int row = rbase + j;
        if (row < ne) {
          const int p = oe + row;
          const int tk = tok[p];
          const float wf = wof[p];
#pragma unroll
          for (int n = 0; n < 4; ++n) {
            const int col = n0 + wc + n * 16 + lr;
            atomicAdd(&out[(size_t)tk * 2048 + col], wf * (acc[m][n][j] + bvn[n]));
          }
        }
      }
    }
  }
}

extern "C" void kernel_launch(void* const* d_in, const int* in_sizes, int n_in,
                              void* d_out, int out_size, void* d_ws, size_t ws_size,
                              hipStream_t stream) {
  const float* x  = (const float*)d_in[0];
  const float* Wg = (const float*)d_in[1];
  const float* bg = (const float*)d_in[2];
  const float* W1 = (const float*)d_in[3];
  const float* b1 = (const float*)d_in[4];
  const float* W2 = (const float*)d_in[5];
  const float* b2 = (const float*)d_in[6];
  float* out = (float*)d_out;
  float* logits = out + (size_t)T_TOK * DDIM;

  char* ws = (char*)d_ws;
  int* cnt    = (int*)(ws);          // 8
  int* off    = (int*)(ws + 64);     // 8
  int* blkcnt = (int*)(ws + 128);    // 16*8
  int* base   = (int*)(ws + 768);    // 16*8
  size_t o = 2048;
  unsigned short* xb   = (unsigned short*)(ws + o); o += (size_t)T_TOK * DDIM * 2;
  unsigned short* W1t  = (unsigned short*)(ws + o); o += (size_t)NEXP * DDIM * HDIM * 2;
  unsigned short* W2t  = (unsigned short*)(ws + o); o += (size_t)NEXP * DDIM * HDIM * 2;
  unsigned short* hbuf = (unsigned short*)(ws + o); o += (size_t)NPAIR * HDIM * 2;
  float* rw  = (float*)(ws + o); o += (size_t)T_TOK * 4 * 4;
  int*   sel = (int*)(ws + o);   o += (size_t)T_TOK * 4 * 4;
  int*   tok = (int*)(ws + o);   o += (size_t)NPAIR * 4;
  float* wof = (float*)(ws + o); o += (size_t)NPAIR * 4;

  hipMemsetAsync(d_out, 0, (size_t)T_TOK * DDIM * sizeof(float), stream);

  transpose_conv_kernel<<<dim3(16, 32, 16), 256, 0, stream>>>(W1, W2, W1t, W2t);
  routing_kernel<<<T_TOK / 4, 256, 0, stream>>>(x, Wg, bg, logits, rw, sel, xb);
  hist_kernel<<<16, 256, 0, stream>>>(sel, blkcnt);
  plan_kernel<<<1, 64, 0, stream>>>(blkcnt, cnt, off, base);
  fill_kernel<<<16, 256, 0, stream>>>(sel, rw, off, base, tok, wof);

  moe_gemm_kernel<<<dim3(1024), 512, 0, stream>>>(0, xb, W1t, b1, cnt, off, tok, wof, hbuf, nullptr);
  moe_gemm_kernel<<<dim3(1024), 512, 0, stream>>>(1, hbuf, W2t, b2, cnt, off, tok, wof, nullptr, out);
}

// Round 13
// 505.858 us; speedup vs baseline: 1.3226x; 1.3226x over previous
//
#include <hip/hip_runtime.h>
#include <hip/hip_bf16.h>
#include <stdint.h>

#define T_TOK 4096
#define DDIM  2048
#define HDIM  2048
#define NEXP  8
#define NPAIR (T_TOK * 4)
#define NT    (DDIM / 64)   // 32 K-tiles of 64
#define NITER (NT / 2)      // 16 iterations, 2 K-tiles each

typedef __attribute__((ext_vector_type(8))) short bf16x8;
typedef __attribute__((ext_vector_type(4))) float f32x4;
typedef __attribute__((ext_vector_type(4))) unsigned short u16x4v;
typedef __attribute__((ext_vector_type(8))) unsigned short u16x8v;

__device__ inline unsigned short f2bf(float f) {
  unsigned u = __builtin_bit_cast(unsigned, f);
  unsigned r = (u + 0x7fffu + ((u >> 16) & 1u)) >> 16;
  return (unsigned short)r;
}

// tanh-form GELU via sigmoid; max |dev| vs exact erf-GELU ~3e-4 << threshold headroom.
__device__ inline float gelu_fast(float v) {
  float u = v + 0.044715f * v * v * v;
  return v / (1.0f + __expf(-1.59576912f * u));
}

// ------- transpose + convert: [z][R=2048][C=2048] fp32 -> [z][C][R] bf16 -------
__global__ __launch_bounds__(256) void transpose_conv_kernel(const float* __restrict__ W1,
                                                             const float* __restrict__ W2,
                                                             unsigned short* __restrict__ W1t,
                                                             unsigned short* __restrict__ W2t) {
  __shared__ float t2[64][129];  // [c][r+pad]
  int z = blockIdx.z;
  const float* src = (z < 8 ? W1 : W2) + (size_t)(z & 7) * DDIM * HDIM;
  unsigned short* dst = (z < 8 ? W1t : W2t) + (size_t)(z & 7) * DDIM * HDIM;
  int r0 = blockIdx.x * 128, c0 = blockIdx.y * 64;
  int tid = threadIdx.x;
  int lr = tid >> 4, lc = (tid & 15) * 4;
#pragma unroll
  for (int i = 0; i < 8; ++i) {
    float4 v = *(const float4*)(src + (size_t)(r0 + i * 16 + lr) * 2048 + c0 + lc);
    t2[lc + 0][i * 16 + lr] = v.x;
    t2[lc + 1][i * 16 + lr] = v.y;
    t2[lc + 2][i * 16 + lr] = v.z;
    t2[lc + 3][i * 16 + lr] = v.w;
  }
  __syncthreads();
  int sc = tid >> 4, rc = (tid & 15) * 8;
#pragma unroll
  for (int q = 0; q < 4; ++q) {
    int c = q * 16 + sc;
    u16x8v o;
#pragma unroll
    for (int k = 0; k < 8; ++k) o[k] = f2bf(t2[c][rc + k]);
    *(u16x8v*)(dst + (size_t)(c0 + c) * 2048 + r0 + rc) = o;
  }
}

// ---------------- routing (fused x->bf16 conversion; NO global atomics) ----------------
__global__ __launch_bounds__(256) void routing_kernel(const float* __restrict__ x,
                                                      const float* __restrict__ Wg,
                                                      const float* __restrict__ bg,
                                                      float* __restrict__ logits,
                                                      float* __restrict__ rw,
                                                      int* __restrict__ sel,
                                                      unsigned short* __restrict__ xb) {
  int t = blockIdx.x * 4 + (threadIdx.x >> 6);
  int l = threadIdx.x & 63;
  const float* xr = x + (size_t)t * DDIM;
  float acc[8] = {0.f, 0.f, 0.f, 0.f, 0.f, 0.f, 0.f, 0.f};
#pragma unroll 1
  for (int i = 0; i < 8; ++i) {
    int d = i * 256 + l * 4;
    float4 xv = *(const float4*)(xr + d);
    u16x4v o;
    o[0] = f2bf(xv.x); o[1] = f2bf(xv.y); o[2] = f2bf(xv.z); o[3] = f2bf(xv.w);
    *(u16x4v*)(xb + (size_t)t * DDIM + d) = o;
    const float* wr = Wg + (size_t)d * 8;
    float xq[4] = {xv.x, xv.y, xv.z, xv.w};
#pragma unroll
    for (int q = 0; q < 4; ++q) {
      float4 w0 = *(const float4*)(wr + q * 8);
      float4 w1 = *(const float4*)(wr + q * 8 + 4);
      acc[0] = fmaf(xq[q], w0.x, acc[0]); acc[1] = fmaf(xq[q], w0.y, acc[1]);
      acc[2] = fmaf(xq[q], w0.z, acc[2]); acc[3] = fmaf(xq[q], w0.w, acc[3]);
      acc[4] = fmaf(xq[q], w1.x, acc[4]); acc[5] = fmaf(xq[q], w1.y, acc[5]);
      acc[6] = fmaf(xq[q], w1.z, acc[6]); acc[7] = fmaf(xq[q], w1.w, acc[7]);
    }
  }
#pragma unroll
  for (int e = 0; e < 8; ++e)
#pragma unroll
    for (int off = 32; off > 0; off >>= 1) acc[e] += __shfl_down(acc[e], off);
  if (l == 0) {
    float lg[8];
#pragma unroll
    for (int e = 0; e < 8; ++e) {
      lg[e] = acc[e] + bg[e];
      logits[(size_t)t * 8 + e] = lg[e];
    }
    float mx = lg[0];
#pragma unroll
    for (int e = 1; e < 8; ++e) mx = fmaxf(mx, lg[e]);
    float p[8];
#pragma unroll
    for (int e = 0; e < 8; ++e) p[e] = expf(lg[e] - mx);
    bool used[8] = {false, false, false, false, false, false, false, false};
    float wsum = 0.f; int se[4]; float pv[4];
    for (int k = 0; k < 4; ++k) {
      int best = 0; float bv = -1.f;
      for (int e = 0; e < 8; ++e)
        if (!used[e] && p[e] > bv) { bv = p[e]; best = e; }
      used[best] = true; se[k] = best; pv[k] = bv; wsum += bv;
    }
    for (int k = 0; k < 4; ++k) {
      rw[t * 4 + k] = pv[k] / wsum;
      sel[t * 4 + k] = se[k];
    }
  }
}

// ---------------- expert-slot planning: per-block LDS histograms, 0 hot global atomics ----------------
__global__ __launch_bounds__(256) void hist_kernel(const int* __restrict__ sel,
                                                   int* __restrict__ blkcnt) {
  __shared__ int h[NEXP];
  if (threadIdx.x < NEXP) h[threadIdx.x] = 0;
  __syncthreads();
  int t = blockIdx.x * 256 + threadIdx.x;
#pragma unroll
  for (int k = 0; k < 4; ++k) atomicAdd(&h[sel[t * 4 + k]], 1);
  __syncthreads();
  if (threadIdx.x < NEXP) blkcnt[blockIdx.x * NEXP + threadIdx.x] = h[threadIdx.x];
}

__global__ void plan_kernel(const int* __restrict__ blkcnt, int* __restrict__ cnt,
                            int* __restrict__ off, int* __restrict__ base) {
  if (threadIdx.x == 0) {
    int c[NEXP];
    for (int e = 0; e < NEXP; ++e) c[e] = 0;
    for (int b = 0; b < 16; ++b)
      for (int e = 0; e < NEXP; ++e) { base[b * NEXP + e] = c[e]; c[e] += blkcnt[b * NEXP + e]; }
    int s = 0;
    for (int e = 0; e < NEXP; ++e) { cnt[e] = c[e]; off[e] = s; s += c[e]; }
  }
}

__global__ __launch_bounds__(256) void fill_kernel(const int* __restrict__ sel,
                                                   const float* __restrict__ rw,
                                                   const int* __restrict__ off,
                                                   const int* __restrict__ base,
                                                   int* __restrict__ tok,
                                                   float* __restrict__ wof) {
  __shared__ int h[NEXP];
  if (threadIdx.x < NEXP) h[threadIdx.x] = 0;
  __syncthreads();
  int t = blockIdx.x * 256 + threadIdx.x;
#pragma unroll
  for (int k = 0; k < 4; ++k) {
    int e = sel[t * 4 + k];
    int r = atomicAdd(&h[e], 1);   // LDS atomic: block-local, fast
    int p = off[e] + base[blockIdx.x * NEXP + e] + r;
    tok[p] = t;
    wof[p] = rw[t * 4 + k];
  }
}

#define GLL(g, l) __builtin_amdgcn_global_load_lds(                         \
    (const __attribute__((address_space(1))) void*)(g),                    \
    (__attribute__((address_space(3))) void*)(l), 16, 0, 0)

#define BARX { __builtin_amdgcn_s_barrier(); __builtin_amdgcn_sched_barrier(0); }
#define WAIT4 { asm volatile("s_waitcnt vmcnt(4)" ::: "memory"); __builtin_amdgcn_sched_barrier(0); }
#define WAIT8 { asm volatile("s_waitcnt vmcnt(8)" ::: "memory"); __builtin_amdgcn_sched_barrier(0); }
#define WAIT0 { asm volatile("s_waitcnt vmcnt(0)" ::: "memory"); __builtin_amdgcn_sched_barrier(0); }

// =============== GEMM1: 256x256 tile, 8 waves, 8-phase, 1 barrier/phase (R9 config) ===============
// Single-path kernel (gather-A + gelu store) in its own codegen context — R9 measured <211us.
#define ST_A0(b, ko) { GLL(aP[0] + (ko), ldsc + (b)*65536 +     0 + stDst); GLL(aP[1] + (ko), ldsc + (b)*65536 +  8192 + stDst); }
#define ST_A1(b, ko) { GLL(aP[2] + (ko), ldsc + (b)*65536 + 16384 + stDst); GLL(aP[3] + (ko), ldsc + (b)*65536 + 24576 + stDst); }
#define ST_B0(b, ko) { GLL(bP[0] + (ko), ldsc + (b)*65536 + 32768 + stDst); GLL(bP[1] + (ko), ldsc + (b)*65536 + 40960 + stDst); }
#define ST_B1(b, ko) { GLL(bP[2] + (ko), ldsc + (b)*65536 + 49152 + stDst); GLL(bP[3] + (ko), ldsc + (b)*65536 + 57344 + stDst); }

#define RD_A(Ab, mq) { _Pragma("unroll") for (int i_ = 0; i_ < 4; ++i_) { \
    af[i_][0] = *(const bf16x8*)&(Ab)[((size_t)(wrlr + ((mq)*4 + i_)*16))*64 + c0]; \
    af[i_][1] = *(const bf16x8*)&(Ab)[((size_t)(wrlr + ((mq)*4 + i_)*16))*64 + c1]; } }
#define RD_B(Bb, nq) { _Pragma("unroll") for (int j_ = 0; j_ < 2; ++j_) { \
    bfr[(nq)*2 + j_][0] = *(const bf16x8*)&(Bb)[((size_t)(wclr + ((nq)*2 + j_)*16))*64 + c0]; \
    bfr[(nq)*2 + j_][1] = *(const bf16x8*)&(Bb)[((size_t)(wclr + ((nq)*2 + j_)*16))*64 + c1]; } }
#define MMA_Q(mq, nq) { __builtin_amdgcn_s_setprio(1); \
  _Pragma("unroll") for (int kk_ = 0; kk_ < 2; ++kk_) \
  _Pragma("unroll") for (int i_ = 0; i_ < 4; ++i_) \
  _Pragma("unroll") for (int j_ = 0; j_ < 2; ++j_) \
    acc[(mq)*4 + i_][(nq)*2 + j_] = __builtin_amdgcn_mfma_f32_16x16x32_bf16( \
        af[i_][kk_], bfr[(nq)*2 + j_][kk_], acc[(mq)*4 + i_][(nq)*2 + j_], 0, 0, 0); \
  __builtin_amdgcn_s_setprio(0); }

__global__ __launch_bounds__(512, 2) void gemm1_kernel(
    const unsigned short* __restrict__ A, const unsigned short* __restrict__ Bt,
    const float* __restrict__ bias, const int* __restrict__ cnt,
    const int* __restrict__ off, const int* __restrict__ tok,
    unsigned short* __restrict__ hout) {
  __shared__ unsigned short lds[65536];  // 128 KiB
  const int bid = blockIdx.x;
  const int e   = bid & 7;
  const int rem = bid >> 3;
  const int bm  = rem & 15;
  const int bn  = rem >> 4;
  const int ne  = cnt[e];
  const int m0  = bm * 256;
  if (m0 >= ne) return;
  const int oe  = off[e];
  const int n0  = bn * 256;
  const int tid = threadIdx.x;
  const int w   = tid >> 6;
  const int l   = tid & 63;

  const int srow = tid >> 3;
  const int scg  = ((tid & 7) ^ (srow & 7)) * 8;
  const unsigned short* aP[4];
  const unsigned short* bP[4];
#pragma unroll
  for (int j = 0; j < 4; ++j) {
    int r = m0 + j * 64 + srow;
    if (r > ne - 1) r = ne - 1;
    aP[j] = A + (size_t)tok[oe + r] * 2048 + scg;
    bP[j] = Bt + ((size_t)e * 2048 + n0 + j * 64 + srow) * 2048 + scg;
  }
  char* ldsc = (char*)lds;
  const int stDst = tid * 16;

  const int wr = (w >> 2) * 128;
  const int wc = (w & 3) * 64;
  const int lr = l & 15;
  const int lq = l >> 4;
  const int cx = lr & 7;
  const int wrlr = wr + lr;
  const int wclr = wc + lr;
  const int c0 = ((0 * 4 + lq) ^ cx) * 8;
  const int c1 = ((1 * 4 + lq) ^ cx) * 8;

  const unsigned short* Ab0 = lds;
  const unsigned short* Bb0 = lds + 16384;
  const unsigned short* Ab1 = lds + 32768;
  const unsigned short* Bb1 = lds + 49152;

  f32x4 acc[8][4];
#pragma unroll
  for (int m = 0; m < 8; ++m)
#pragma unroll
    for (int n = 0; n < 4; ++n) acc[m][n] = (f32x4){0.f, 0.f, 0.f, 0.f};

  ST_B0(0, 0); ST_B1(0, 0); ST_A0(0, 0); ST_A1(0, 0);
  ST_B0(1, 64); ST_B1(1, 64);
  WAIT4; BARX;

#pragma unroll 1
  for (int it = 0; it < NITER; ++it) {
    const int ko1 = (2 * it + 1) * 64;
    const int ko2 = (2 * it + 2) * 64;
    const int ko3 = (2 * it + 3) * 64;
    const bool pf = (it < NITER - 1);
    bf16x8 af[4][2], bfr[4][2];

    ST_A0(1, ko1);
    RD_A(Ab0, 0); RD_B(Bb0, 0);
    MMA_Q(0, 0); BARX;
    ST_A1(1, ko1);
    RD_B(Bb0, 1);
    MMA_Q(0, 1); BARX;
    if (pf) ST_B0(0, ko2);
    RD_A(Ab0, 1);
    MMA_Q(1, 0); BARX;
    if (pf) ST_B1(0, ko2);
    MMA_Q(1, 1);
    if (pf) { WAIT4; } else { WAIT0; }
    BARX;
    if (pf) ST_A0(0, ko2);
    RD_A(Ab1, 0); RD_B(Bb1, 0);
    MMA_Q(0, 0); BARX;
    if (pf) ST_A1(0, ko2);
    RD_B(Bb1, 1);
    MMA_Q(0, 1); BARX;
    if (pf) ST_B0(1, ko3);
    RD_A(Ab1, 1);
    MMA_Q(1, 0); BARX;
    if (pf) ST_B1(1, ko3);
    MMA_Q(1, 1);
    if (pf) { WAIT4; }
    BARX;
  }

  const int rj = lq * 4;
  float bvn[4];
#pragma unroll
  for (int n = 0; n < 4; ++n) bvn[n] = bias[e * 2048 + n0 + wc + n * 16 + lr];
#pragma unroll
  for (int m = 0; m < 8; ++m) {
    const int rbase = m0 + wr + m * 16 + rj;
#pragma unroll
    for (int j = 0; j < 4; ++j) {
      const int row = rbase + j;
      if (row < ne) {
#pragma unroll
        for (int n = 0; n < 4; ++n) {
          const int col = n0 + wc + n * 16 + lr;
          float v = acc[m][n][j] + bvn[n];
          hout[(size_t)(oe + row) * 2048 + col] = f2bf(gelu_fast(v));
        }
      }
    }
  }
}

// =============== GEMM2: 128x128 tile, 4 waves, 64 KiB dbuf, counted-vmcnt 2-phase (R9 config) ===============
__global__ __launch_bounds__(256) void gemm2_kernel(
    const unsigned short* __restrict__ A, const unsigned short* __restrict__ Bt,
    const float* __restrict__ bias, const int* __restrict__ cnt,
    const int* __restrict__ off, const int* __restrict__ tok,
    const float* __restrict__ wof, float* __restrict__ out) {
  __shared__ unsigned short lds[32768];  // 64 KiB
  const int bid = blockIdx.x;
  const int e   = bid & 7;
  const int rem = bid >> 3;
  const int bm  = rem & 31;
  const int bn  = rem >> 5;
  const int ne  = cnt[e];
  const int m0  = bm * 128;
  if (m0 >= ne) return;
  const int oe  = off[e];
  const int n0  = bn * 128;
  const int tid = threadIdx.x;
  const int w   = tid >> 6;
  const int l   = tid & 63;

  const int srow = tid >> 3;
  const int scg  = ((tid & 7) ^ (srow & 7)) * 8;
  const unsigned short* aP[4];
  const unsigned short* bP[4];
#pragma unroll
  for (int j = 0; j < 4; ++j) {
    int r = m0 + j * 32 + srow;
    if (r > ne - 1) r = ne - 1;
    aP[j] = A + (size_t)(oe + r) * 2048 + scg;
    bP[j] = Bt + ((size_t)e * 2048 + n0 + j * 32 + srow) * 2048 + scg;
  }
  char* ldsc = (char*)lds;
  const int stDst = tid * 16;

  const int wr = (w >> 1) * 64;
  const int wc = (w & 1) * 64;
  const int lr = l & 15;
  const int lq = l >> 4;
  const int cx = lr & 7;
  const int wrlr = wr + lr;
  const int wclr = wc + lr;
  const int c0 = ((0 * 4 + lq) ^ cx) * 8;
  const int c1 = ((1 * 4 + lq) ^ cx) * 8;

  f32x4 acc[4][4];
#pragma unroll
  for (int m = 0; m < 4; ++m)
#pragma unroll
    for (int n = 0; n < 4; ++n) acc[m][n] = (f32x4){0.f, 0.f, 0.f, 0.f};

#pragma unroll
  for (int j = 0; j < 4; ++j) GLL(aP[j], ldsc + j * 4096 + stDst);
#pragma unroll
  for (int j = 0; j < 4; ++j) GLL(bP[j], ldsc + 16384 + j * 4096 + stDst);

#pragma unroll 1
  for (int t = 0; t < NT; ++t) {
    if (t < NT - 1) {
      const int ko = (t + 1) * 64;
      char* dstA = ldsc + ((t + 1) & 1) * 32768;
#pragma unroll
      for (int j = 0; j < 4; ++j) GLL(aP[j] + ko, dstA + j * 4096 + stDst);
#pragma unroll
      for (int j = 0; j < 4; ++j) GLL(bP[j] + ko, dstA + 16384 + j * 4096 + stDst);
      WAIT8;
    } else {
      WAIT0;
    }
    __builtin_amdgcn_s_barrier();

    const unsigned short* Ab = lds + (t & 1) * 16384;
    const unsigned short* Bb = Ab + 8192;
    bf16x8 af[4][2], bfr[4][2];
#pragma unroll
    for (int m = 0; m < 4; ++m) {
      af[m][0] = *(const bf16x8*)&Ab[(size_t)(wrlr + m * 16) * 64 + c0];
      af[m][1] = *(const bf16x8*)&Ab[(size_t)(wrlr + m * 16) * 64 + c1];
    }
#pragma unroll
    for (int n = 0; n < 4; ++n) {
      bfr[n][0] = *(const bf16x8*)&Bb[(size_t)(wclr + n * 16) * 64 + c0];
      bfr[n][1] = *(const bf16x8*)&Bb[(size_t)(wclr + n * 16) * 64 + c1];
    }
    __builtin_amdgcn_s_setprio(1);
#pragma unroll
    for (int kk = 0; kk < 2; ++kk)
#pragma unroll
      for (int m = 0; m < 4; ++m)
#pragma unroll
        for (int n = 0; n < 4; ++n)
          acc[m][n] = __builtin_amdgcn_mfma_f32_16x16x32_bf16(af[m][kk], bfr[n][kk], acc[m][n], 0, 0, 0);
    __builtin_amdgcn_s_setprio(0);
    __builtin_amdgcn_s_barrier();
  }

  const int rj = lq * 4;
  float bvn[4];
#pragma unroll
  for (int n = 0; n < 4; ++n) bvn[n] = bias[e * 2048 + n0 + wc + n * 16 + lr];
#pragma unroll
  for (int m = 0; m < 4; ++m) {
    const int rbase = m0 + wr + m * 16 + rj;
#pragma unroll
    for (int j = 0; j < 4; ++j) {
      const int row = rbase + j;
      if (row < ne) {
        const int p = oe + row;
        const int tk = tok[p];
        const float wf = wof[p];
#pragma unroll
        for (int n = 0; n < 4; ++n) {
          const int col = n0 + wc + n * 16 + lr;
          atomicAdd(&out[(size_t)tk * 2048 + col], wf * (acc[m][n][j] + bvn[n]));
        }
      }
    }
  }
}

extern "C" void kernel_launch(void* const* d_in, const int* in_sizes, int n_in,
                              void* d_out, int out_size, void* d_ws, size_t ws_size,
                              hipStream_t stream) {
  const float* x  = (const float*)d_in[0];
  const float* Wg = (const float*)d_in[1];
  const float* bg = (const float*)d_in[2];
  const float* W1 = (const float*)d_in[3];
  const float* b1 = (const float*)d_in[4];
  const float* W2 = (const float*)d_in[5];
  const float* b2 = (const float*)d_in[6];
  float* out = (float*)d_out;
  float* logits = out + (size_t)T_TOK * DDIM;

  char* ws = (char*)d_ws;
  int* cnt    = (int*)(ws);          // 8
  int* off    = (int*)(ws + 64);     // 8
  int* blkcnt = (int*)(ws + 128);    // 16*8
  int* base   = (int*)(ws + 768);    // 16*8
  size_t o = 2048;
  unsigned short* xb   = (unsigned short*)(ws + o); o += (size_t)T_TOK * DDIM * 2;
  unsigned short* W1t  = (unsigned short*)(ws + o); o += (size_t)NEXP * DDIM * HDIM * 2;
  unsigned short* W2t  = (unsigned short*)(ws + o); o += (size_t)NEXP * DDIM * HDIM * 2;
  unsigned short* hbuf = (unsigned short*)(ws + o); o += (size_t)NPAIR * HDIM * 2;
  float* rw  = (float*)(ws + o); o += (size_t)T_TOK * 4 * 4;
  int*   sel = (int*)(ws + o);   o += (size_t)T_TOK * 4 * 4;
  int*   tok = (int*)(ws + o);   o += (size_t)NPAIR * 4;
  float* wof = (float*)(ws + o); o += (size_t)NPAIR * 4;

  hipMemsetAsync(d_out, 0, (size_t)T_TOK * DDIM * sizeof(float), stream);

  transpose_conv_kernel<<<dim3(16, 32, 16), 256, 0, stream>>>(W1, W2, W1t, W2t);
  routing_kernel<<<T_TOK / 4, 256, 0, stream>>>(x, Wg, bg, logits, rw, sel, xb);
  hist_kernel<<<16, 256, 0, stream>>>(sel, blkcnt);
  plan_kernel<<<1, 64, 0, stream>>>(blkcnt, cnt, off, base);
  fill_kernel<<<16, 256, 0, stream>>>(sel, rw, off, base, tok, wof);

  gemm1_kernel<<<dim3(1024), 512, 0, stream>>>(xb, W1t, b1, cnt, off, tok, hbuf);
  gemm2_kernel<<<dim3(4096), 256, 0, stream>>>(hbuf, W2t, b2, cnt, off, tok, wof, out);
}